// Round 9
// baseline (186.594 us; speedup 1.0000x reference)
//
#include <hip/hip_runtime.h>

typedef unsigned short u16;
typedef unsigned int u32;
typedef short bf16x8 __attribute__((ext_vector_type(8)));
typedef float f32x4 __attribute__((ext_vector_type(4)));

constexpr int Bb = 2, Cc = 1024, Tt = 2048, Hh = 16, Dd = 64;

__device__ __forceinline__ u16 f2bf(float f) {
    union { float f; u32 i; } c; c.f = f;
    u32 u = c.i;
    u32 r = (u + 0x7FFFu + ((u >> 16) & 1u)) >> 16;
    return (u16)r;
}
__device__ __forceinline__ u32 pk_bf2(float lo, float hi) {
    union { float f; u32 i; } a, b; a.f = lo; b.f = hi;
    u32 ua = a.i + 0x8000u, ub = b.i + 0x8000u;
    return (ub & 0xFFFF0000u) | (ua >> 16);
}
// scale packed bf16x2 by 0.125 exactly
__device__ __forceinline__ u32 scl2(u32 w) {
    union { float f; u32 i; } lo, hi;
    lo.i = w << 16; hi.i = w & 0xFFFF0000u;
    lo.f *= 0.125f; hi.f *= 0.125f;
    return (hi.i & 0xFFFF0000u) | (lo.i >> 16);
}
__device__ __forceinline__ void gl_lds16(const u16* g, u16* l) {
    __builtin_amdgcn_global_load_lds(
        (const __attribute__((address_space(1))) u32*)(const void*)g,
        (__attribute__((address_space(3))) u32*)(void*)l, 16, 0, 0);
}

// ------- prep: blocks 0..1 = per-batch mask scan; blocks 2.. = weight fp32->bf16 -------
__global__ __launch_bounds__(256) void prep(const int* __restrict__ mask,
                                            int* __restrict__ pfx,
                                            int* __restrict__ tmap,
                                            int* __restrict__ nk,
                                            const float* __restrict__ w0,
                                            const float* __restrict__ w1,
                                            const float* __restrict__ w2,
                                            const float* __restrict__ w3,
                                            u16* __restrict__ wout) {
    if (blockIdx.x < 2) {
        __shared__ int part[256];
        int b = blockIdx.x;
        const int* m = mask + b * Tt;
        int t8 = threadIdx.x * 8;
        int v[8], s = 0;
#pragma unroll
        for (int i = 0; i < 8; i++) { v[i] = m[t8 + i] ? 1 : 0; s += v[i]; }
        part[threadIdx.x] = s;
        __syncthreads();
        for (int off = 1; off < 256; off <<= 1) {
            int val = (threadIdx.x >= off) ? part[threadIdx.x - off] : 0;
            __syncthreads();
            part[threadIdx.x] += val;
            __syncthreads();
        }
        int run = part[threadIdx.x] - s;
#pragma unroll
        for (int i = 0; i < 8; i++) {
            pfx[b * Tt + t8 + i] = run;
            if (v[i]) { tmap[b * Tt + run] = t8 + i; run++; }
        }
        if (threadIdx.x == 255) nk[b] = part[255];
    } else {
        int bi = blockIdx.x - 2;
        int wsel = bi >> 10, blk = bi & 1023;
        const float* in = (wsel == 0) ? w0 : (wsel == 1) ? w1 : (wsel == 2) ? w2 : w3;
        u16* o = wout + (size_t)wsel * Cc * Cc;
        int i = (blk * 256 + threadIdx.x) * 4;
        float4 v = *(const float4*)(in + i);
        o[i + 0] = f2bf(v.x);
        o[i + 1] = f2bf(v.y);
        o[i + 2] = f2bf(v.z);
        o[i + 3] = f2bf(v.w);
    }
}

// ------- x transpose+convert+COMPACT: fp32 [b][c][t] -> bf16 xTc[b][pfx[t]][c] -------
__global__ __launch_bounds__(256) void transpose_x(const float* __restrict__ x,
                                                   const int* __restrict__ mask,
                                                   const int* __restrict__ pfx,
                                                   u16* __restrict__ xT) {
    __shared__ u16 tile[32][33];
    int b = blockIdx.z;
    int t0 = blockIdx.x * 32, c0 = blockIdx.y * 32;
    int tx = threadIdx.x, ty = threadIdx.y;
    const float* xb = x + (size_t)b * Cc * Tt;
    u16* xTb = xT + (size_t)b * Tt * Cc;
#pragma unroll
    for (int i = 0; i < 4; i++) {
        int r = ty + i * 8;
        tile[r][tx] = f2bf(xb[(size_t)(c0 + r) * Tt + t0 + tx]);
    }
    __syncthreads();
#pragma unroll
    for (int i = 0; i < 4; i++) {
        int r = ty + i * 8;
        int t = t0 + r;
        if (mask[b * Tt + t]) {
            int slot = pfx[b * Tt + t];
            xTb[(size_t)slot * Cc + c0 + tx] = tile[tx][r];
        }
    }
}

// ============ fused QKV GEMM on COMPACTED rows: 128x128, BK=64 ============
__global__ __launch_bounds__(256) void gemm_qkv(const u16* __restrict__ A,
                                                const u16* __restrict__ Bt,
                                                const float* __restrict__ b0,
                                                const float* __restrict__ b1,
                                                const float* __restrict__ b2,
                                                const int* __restrict__ nk,
                                                u16* __restrict__ qb, u16* __restrict__ kb,
                                                u16* __restrict__ vT) {
    constexpr int K = Cc;
    __shared__ u16 Alds[128 * 64];
    __shared__ u16 Blds[128 * 64];
    int n0 = blockIdx.x * 128, m0 = blockIdx.y * 128;
    int bb = m0 >> 11;
    if ((m0 & 2047) >= nk[bb]) return;
    int tid = threadIdx.x;
    int lane = tid & 63, wave = tid >> 6;
    int quad = lane >> 4, id15 = lane & 15;
    int wm0 = (wave & 1) * 64, wn0 = (wave >> 1) * 64;
    int srow = lane >> 3;
    int scol = ((lane & 7) ^ srow) * 8;
    int sw = id15 & 7;

    f32x4 acc[4][4] = {};  // [ni][mi]

    for (int k0 = 0; k0 < K; k0 += 64) {
        __syncthreads();
#pragma unroll
        for (int t = 0; t < 4; t++) {
            int g = wave * 4 + t;
            int r = g * 8 + srow;
            gl_lds16(A + (size_t)(m0 + r) * K + k0 + scol, &Alds[g * 512]);
            gl_lds16(Bt + (size_t)(n0 + r) * K + k0 + scol, &Blds[g * 512]);
        }
        __syncthreads();
#pragma unroll
        for (int hf = 0; hf < 2; hf++) {
            bf16x8 af[4], bf[4];
#pragma unroll
            for (int i = 0; i < 4; i++) {
                int c = (((hf << 2) | quad) ^ sw) * 8;
                af[i] = *(const bf16x8*)(&Alds[(wm0 + i * 16 + id15) * 64 + c]);
                bf[i] = *(const bf16x8*)(&Blds[(wn0 + i * 16 + id15) * 64 + c]);
            }
#pragma unroll
            for (int ni = 0; ni < 4; ni++)
#pragma unroll
                for (int mi = 0; mi < 4; mi++)
                    acc[ni][mi] = __builtin_amdgcn_mfma_f32_16x16x32_bf16(
                        bf[ni], af[mi], acc[ni][mi], 0, 0, 0);
        }
    }

    int mt0 = (m0 & 2047) + wm0;
#pragma unroll
    for (int ni = 0; ni < 4; ni++) {
        int nr = n0 + wn0 + ni * 16 + quad * 4;
        int sect = nr >> 10;
        int nn = nr & 1023;
        int h = nn >> 6, d0 = nn & 63;
        const float* bp_ = (sect == 0) ? b0 : (sect == 1) ? b1 : b2;
        float4 bv4 = *(const float4*)(bp_ + nn);
        if (sect < 2) {
            u16* dst = ((sect == 0) ? qb : kb) + ((size_t)bb * Hh + h) * Tt * (size_t)Dd;
#pragma unroll
            for (int mi = 0; mi < 4; mi++) {
                int mt = mt0 + mi * 16 + id15;
                uint2 w;
                w.x = pk_bf2(acc[ni][mi][0] + bv4.x, acc[ni][mi][1] + bv4.y);
                w.y = pk_bf2(acc[ni][mi][2] + bv4.z, acc[ni][mi][3] + bv4.w);
                *(uint2*)(dst + (size_t)mt * Dd + d0) = w;
            }
        } else {
            u16* dst = vT + ((size_t)bb * Hh + h) * Dd * (size_t)Tt;
#pragma unroll
            for (int mi = 0; mi < 4; mi++) {
                int mt = mt0 + mi * 16 + id15;
                dst[(size_t)(d0 + 0) * Tt + mt] = f2bf(acc[ni][mi][0] + bv4.x);
                dst[(size_t)(d0 + 1) * Tt + mt] = f2bf(acc[ni][mi][1] + bv4.y);
                dst[(size_t)(d0 + 2) * Tt + mt] = f2bf(acc[ni][mi][2] + bv4.z);
                dst[(size_t)(d0 + 3) * Tt + mt] = f2bf(acc[ni][mi][3] + bv4.w);
            }
        }
    }
}

// ============ proj GEMM (full-M): 64n x 128m, BK=64; (0,0) block also writes mask tail ====
__global__ __launch_bounds__(256) void gemm_proj(const u16* __restrict__ A,
                                                 const u16* __restrict__ Bt,
                                                 const float* __restrict__ b0,
                                                 const int* __restrict__ mask,
                                                 float* __restrict__ out,
                                                 float* __restrict__ outTail) {
    constexpr int K = Cc;
    __shared__ u16 Alds[128 * 64];
    __shared__ u16 Blds[64 * 64];
    int n0 = blockIdx.x * 64, m0 = blockIdx.y * 128;
    int tid = threadIdx.x;
    if (outTail && blockIdx.x == 0 && blockIdx.y == 0) {
        for (int i = tid; i < Bb * Tt; i += 256) outTail[i] = mask[i] ? 1.0f : 0.0f;
    }
    int lane = tid & 63, wave = tid >> 6;
    int quad = lane >> 4, id15 = lane & 15;
    int wn0 = (wave & 1) * 32, wm0 = (wave >> 1) * 64;
    int srow = lane >> 3;
    int scol = ((lane & 7) ^ srow) * 8;
    int sw = id15 & 7;

    f32x4 acc[2][4] = {};

    for (int k0 = 0; k0 < K; k0 += 64) {
        __syncthreads();
#pragma unroll
        for (int t = 0; t < 4; t++) {
            int g = wave * 4 + t;
            gl_lds16(A + (size_t)(m0 + g * 8 + srow) * K + k0 + scol, &Alds[g * 512]);
        }
#pragma unroll
        for (int t = 0; t < 2; t++) {
            int g = wave * 2 + t;
            gl_lds16(Bt + (size_t)(n0 + g * 8 + srow) * K + k0 + scol, &Blds[g * 512]);
        }
        __syncthreads();
#pragma unroll
        for (int hf = 0; hf < 2; hf++) {
            bf16x8 af[4], bf[2];
            int c = (((hf << 2) | quad) ^ sw) * 8;
#pragma unroll
            for (int i = 0; i < 4; i++)
                af[i] = *(const bf16x8*)(&Alds[(wm0 + i * 16 + id15) * 64 + c]);
#pragma unroll
            for (int i = 0; i < 2; i++)
                bf[i] = *(const bf16x8*)(&Blds[(wn0 + i * 16 + id15) * 64 + c]);
#pragma unroll
            for (int ni = 0; ni < 2; ni++)
#pragma unroll
                for (int mi = 0; mi < 4; mi++)
                    acc[ni][mi] = __builtin_amdgcn_mfma_f32_16x16x32_bf16(
                        bf[ni], af[mi], acc[ni][mi], 0, 0, 0);
        }
    }

    int bb = m0 >> 11;
    int mt0 = (m0 & 2047) + wm0;
#pragma unroll
    for (int ni = 0; ni < 2; ni++) {
        int nr = n0 + wn0 + ni * 16 + quad * 4;
        float4 bv4 = *(const float4*)(b0 + nr);
#pragma unroll
        for (int mi = 0; mi < 4; mi++) {
            int m = mt0 + mi * 16 + id15;
            int mg = (bb << 11) + m;
            float mm = (float)mask[mg];
            float* o = out + ((size_t)bb * Cc + nr) * Tt + m;
            o[0 * Tt] = (acc[ni][mi][0] + bv4.x) * mm;
            o[1 * Tt] = (acc[ni][mi][1] + bv4.y) * mm;
            o[2 * Tt] = (acc[ni][mi][2] + bv4.z) * mm;
            o[3 * Tt] = (acc[ni][mi][3] + bv4.w) * mm;
        }
    }
}

// ---------------- flash attention, COMPACTED, Q-tile 64 (16 queries/wave) ----------------
// 2 blocks/CU (LDS 64 KB): 8 waves/CU for latency hiding. 128-key double-buffered
// LDS chunks via global_load_lds; no mask logic except final-chunk slot select.
__global__ __launch_bounds__(256) void attn(const u16* __restrict__ q,
                                            const u16* __restrict__ kk,
                                            const u16* __restrict__ vT,
                                            const int* __restrict__ tmap,
                                            const int* __restrict__ nk,
                                            u16* __restrict__ o_buf) {
    __shared__ u16 Kl[2][128 * 64];
    __shared__ u16 Vl[2][64 * 128];
    int bh = blockIdx.y;
    int b = bh >> 4, h = bh & 15;
    int t0 = blockIdx.x * 64;
    int nkb = nk[b];
    if (t0 >= nkb) return;
    int tid = threadIdx.x;
    int lane = tid & 63, wave = tid >> 6;
    int quad = lane >> 4, id15 = lane & 15;
    int wq = t0 + wave * 16;
    const u16* qb = q + (size_t)bh * Tt * Dd;
    const u16* kb = kk + (size_t)bh * Tt * Dd;
    const u16* vb = vT + (size_t)bh * Dd * Tt;

    // Q fragment (16 queries), 0.125 scale folded in
    union { uint4 r; bf16x8 v; } qf[2];
#pragma unroll
    for (int hf = 0; hf < 2; hf++) {
        uint4 r = *(const uint4*)(qb + (size_t)(wq + id15) * Dd + hf * 32 + quad * 8);
        qf[hf].r.x = scl2(r.x);
        qf[hf].r.y = scl2(r.y);
        qf[hf].r.z = scl2(r.z);
        qf[hf].r.w = scl2(r.w);
    }

    int srowK = lane >> 3;
    int scolK = ((lane & 7) ^ srowK) * 8;
    int srowV = lane >> 4;
    int sw = id15 & 7;

    float l = 0.0f;
    f32x4 accO[4] = {};

    // prologue: stage chunk 0 into buf 0
#pragma unroll
    for (int t = 0; t < 4; t++) {
        int g = wave * 4 + t;
        gl_lds16(kb + (size_t)(g * 8 + srowK) * Dd + scolK, &Kl[0][g * 512]);
        int d = g * 4 + srowV;
        int sc = (lane & 15) ^ (4 * (g & 1) + srowV);
        gl_lds16(vb + (size_t)d * Tt + sc * 8, &Vl[0][g * 512]);
    }

    int shA = ((quad & 1) * 2) * 16 + id15;
    int shB = shA + 16;

    int cbuf = 0;
    for (int j0 = 0; j0 < nkb; j0 += 128, cbuf ^= 1) {
        __syncthreads();
        if (j0 + 128 < nkb) {
            int bn = cbuf ^ 1, jn = j0 + 128;
#pragma unroll
            for (int t = 0; t < 4; t++) {
                int g = wave * 4 + t;
                gl_lds16(kb + (size_t)(jn + g * 8 + srowK) * Dd + scolK, &Kl[bn][g * 512]);
                int d = g * 4 + srowV;
                int sc = (lane & 15) ^ (4 * (g & 1) + srowV);
                gl_lds16(vb + (size_t)d * Tt + jn + sc * 8, &Vl[bn][g * 512]);
            }
        }
        const u16* Kb = Kl[cbuf];
        const u16* Vb = Vl[cbuf];

        // S^T: 128 keys x 16 queries
        f32x4 st[8] = {};
#pragma unroll
        for (int kt = 0; kt < 8; kt++) {
            int krow = kt * 16 + id15;
#pragma unroll
            for (int hf = 0; hf < 2; hf++) {
                bf16x8 kf = *(const bf16x8*)(Kb + krow * 64 + (((hf << 2) | quad) ^ sw) * 8);
                st[kt] = __builtin_amdgcn_mfma_f32_16x16x32_bf16(kf, qf[hf].v, st[kt], 0, 0, 0);
            }
        }

        // tail chunk: dead key slots -> -inf before exp
        if (j0 + 128 > nkb) {
#pragma unroll
            for (int kt = 0; kt < 8; kt++) {
                int jb = j0 + kt * 16 + quad * 4;
#pragma unroll
                for (int r = 0; r < 4; r++)
                    if (jb + r >= nkb) st[kt][r] = -1e30f;
            }
        }

        u32 pkk[4][2][2];
#pragma unroll
        for (int kt = 0; kt < 8; kt++) {
            float p0 = __expf(st[kt][0]);
            float p1 = __expf(st[kt][1]);
            float p2 = __expf(st[kt][2]);
            float p3 = __expf(st[kt][3]);
            l += (p0 + p1) + (p2 + p3);
            pkk[kt >> 1][kt & 1][0] = pk_bf2(p0, p1);
            pkk[kt >> 1][kt & 1][1] = pk_bf2(p2, p3);
        }

#pragma unroll
        for (int g = 0; g < 4; g++) {
            union { u32 u[4]; bf16x8 v; } pf;
            u32 a0 = (u32)__shfl((int)pkk[g][0][0], shA);
            u32 a1 = (u32)__shfl((int)pkk[g][0][1], shA);
            u32 a2 = (u32)__shfl((int)pkk[g][0][0], shB);
            u32 a3 = (u32)__shfl((int)pkk[g][0][1], shB);
            u32 c0 = (u32)__shfl((int)pkk[g][1][0], shA);
            u32 c1 = (u32)__shfl((int)pkk[g][1][1], shA);
            u32 c2 = (u32)__shfl((int)pkk[g][1][0], shB);
            u32 c3 = (u32)__shfl((int)pkk[g][1][1], shB);
            pf.u[0] = (quad < 2) ? a0 : c0;
            pf.u[1] = (quad < 2) ? a1 : c1;
            pf.u[2] = (quad < 2) ? a2 : c2;
            pf.u[3] = (quad < 2) ? a3 : c3;
#pragma unroll
            for (int dt = 0; dt < 4; dt++) {
                int drow = dt * 16 + id15;
                bf16x8 vf = *(const bf16x8*)(Vb + drow * 128 + (((g << 2) | quad) ^ sw) * 8);
                accO[dt] = __builtin_amdgcn_mfma_f32_16x16x32_bf16(vf, pf.v, accO[dt], 0, 0, 0);
            }
        }
    }

    int slot = wq + id15;
    bool ok = slot < nkb;
    int torig = ok ? tmap[b * Tt + slot] : 0;
    float lv = l;
    lv += __shfl_xor(lv, 16);
    lv += __shfl_xor(lv, 32);
    float inv = 1.0f / lv;
    if (ok) {
#pragma unroll
        for (int dt = 0; dt < 4; dt++) {
            uint2 w;
            w.x = pk_bf2(accO[dt][0] * inv, accO[dt][1] * inv);
            w.y = pk_bf2(accO[dt][2] * inv, accO[dt][3] * inv);
            *(uint2*)(o_buf + ((size_t)b * Tt + torig) * Cc + h * Dd + dt * 16 + quad * 4) = w;
        }
    }
}

extern "C" void kernel_launch(void* const* d_in, const int* in_sizes, int n_in,
                              void* d_out, int out_size, void* d_ws, size_t ws_size,
                              hipStream_t stream) {
    const float* x  = (const float*)d_in[0];
    const int* mask = (const int*)d_in[1];
    const float* Wq = (const float*)d_in[2];
    const float* bq = (const float*)d_in[3];
    const float* Wk = (const float*)d_in[4];
    const float* bk = (const float*)d_in[5];
    const float* Wv = (const float*)d_in[6];
    const float* bv = (const float*)d_in[7];
    const float* Wp = (const float*)d_in[8];
    const float* bp = (const float*)d_in[9];
    float* out = (float*)d_out;

    size_t sz = (size_t)Bb * Tt * Cc;
    size_t wsz = (size_t)Cc * Cc;
    u16* xT = (u16*)d_ws;
    u16* qb = xT + sz;
    u16* kb = qb + sz;
    u16* vT = kb + sz;
    u16* wq16 = vT + sz;   // wq/wk/wv contiguous => fused [3072][1024] B matrix
    u16* wp16 = wq16 + 3 * wsz;
    int* pfx  = (int*)(wp16 + wsz);
    int* tmap = pfx + Bb * Tt;
    int* nkp  = tmap + Bb * Tt;
    u16* ob = xT;  // reuse xT region (stream-ordered)

    float* outTail = (out_size >= Bb * Cc * Tt + Bb * Tt)
                         ? out + (size_t)Bb * Cc * Tt : nullptr;

    prep<<<2 + 4 * (int)(wsz / 1024), 256, 0, stream>>>(
        mask, pfx, tmap, nkp, Wq, Wk, Wv, Wp, wq16);
    transpose_x<<<dim3(Tt / 32, Cc / 32, Bb), dim3(32, 8), 0, stream>>>(x, mask, pfx, xT);
    gemm_qkv<<<dim3(3 * Cc / 128, Bb * Tt / 128), 256, 0, stream>>>(
        xT, wq16, bq, bk, bv, nkp, qb, kb, vT);
    attn<<<dim3(Tt / 64, Bb * Hh), 256, 0, stream>>>(qb, kb, vT, tmap, nkp, ob);
    gemm_proj<<<dim3(Cc / 64, Bb * Tt / 128), 256, 0, stream>>>(
        ob, wp16, bp, mask, out, outTail);
}

// Round 10
// 184.605 us; speedup vs baseline: 1.0108x; 1.0108x over previous
//
#include <hip/hip_runtime.h>

typedef unsigned short u16;
typedef unsigned int u32;
typedef short bf16x8 __attribute__((ext_vector_type(8)));
typedef float f32x4 __attribute__((ext_vector_type(4)));

constexpr int Bb = 2, Cc = 1024, Tt = 2048, Hh = 16, Dd = 64;

__device__ __forceinline__ u16 f2bf(float f) {
    union { float f; u32 i; } c; c.f = f;
    u32 u = c.i;
    u32 r = (u + 0x7FFFu + ((u >> 16) & 1u)) >> 16;
    return (u16)r;
}
__device__ __forceinline__ u32 pk_bf2(float lo, float hi) {
    union { float f; u32 i; } a, b; a.f = lo; b.f = hi;
    u32 ua = a.i + 0x8000u, ub = b.i + 0x8000u;
    return (ub & 0xFFFF0000u) | (ua >> 16);
}
// scale packed bf16x2 by 0.125 exactly
__device__ __forceinline__ u32 scl2(u32 w) {
    union { float f; u32 i; } lo, hi;
    lo.i = w << 16; hi.i = w & 0xFFFF0000u;
    lo.f *= 0.125f; hi.f *= 0.125f;
    return (hi.i & 0xFFFF0000u) | (lo.i >> 16);
}
__device__ __forceinline__ void gl_lds16(const u16* g, u16* l) {
    __builtin_amdgcn_global_load_lds(
        (const __attribute__((address_space(1))) u32*)(const void*)g,
        (__attribute__((address_space(3))) u32*)(void*)l, 16, 0, 0);
}

// ------- prep: blocks 0..1 = per-batch mask scan; blocks 2.. = weight fp32->bf16 -------
__global__ __launch_bounds__(256) void prep(const int* __restrict__ mask,
                                            int* __restrict__ pfx,
                                            int* __restrict__ tmap,
                                            int* __restrict__ nk,
                                            const float* __restrict__ w0,
                                            const float* __restrict__ w1,
                                            const float* __restrict__ w2,
                                            const float* __restrict__ w3,
                                            u16* __restrict__ wout) {
    if (blockIdx.x < 2) {
        __shared__ int part[256];
        int b = blockIdx.x;
        const int* m = mask + b * Tt;
        int t8 = threadIdx.x * 8;
        int v[8], s = 0;
#pragma unroll
        for (int i = 0; i < 8; i++) { v[i] = m[t8 + i] ? 1 : 0; s += v[i]; }
        part[threadIdx.x] = s;
        __syncthreads();
        for (int off = 1; off < 256; off <<= 1) {
            int val = (threadIdx.x >= off) ? part[threadIdx.x - off] : 0;
            __syncthreads();
            part[threadIdx.x] += val;
            __syncthreads();
        }
        int run = part[threadIdx.x] - s;
#pragma unroll
        for (int i = 0; i < 8; i++) {
            pfx[b * Tt + t8 + i] = run;
            if (v[i]) { tmap[b * Tt + run] = t8 + i; run++; }
        }
        if (threadIdx.x == 255) nk[b] = part[255];
    } else {
        int bi = blockIdx.x - 2;
        int wsel = bi >> 10, blk = bi & 1023;
        const float* in = (wsel == 0) ? w0 : (wsel == 1) ? w1 : (wsel == 2) ? w2 : w3;
        u16* o = wout + (size_t)wsel * Cc * Cc;
        int i = (blk * 256 + threadIdx.x) * 4;
        float4 v = *(const float4*)(in + i);
        o[i + 0] = f2bf(v.x);
        o[i + 1] = f2bf(v.y);
        o[i + 2] = f2bf(v.z);
        o[i + 3] = f2bf(v.w);
    }
}

// ------- x transpose+convert+COMPACT: fp32 [b][c][t] -> bf16 xTc[b][pfx[t]][c] -------
__global__ __launch_bounds__(256) void transpose_x(const float* __restrict__ x,
                                                   const int* __restrict__ mask,
                                                   const int* __restrict__ pfx,
                                                   u16* __restrict__ xT) {
    __shared__ u16 tile[32][33];
    int b = blockIdx.z;
    int t0 = blockIdx.x * 32, c0 = blockIdx.y * 32;
    int tx = threadIdx.x, ty = threadIdx.y;
    const float* xb = x + (size_t)b * Cc * Tt;
    u16* xTb = xT + (size_t)b * Tt * Cc;
#pragma unroll
    for (int i = 0; i < 4; i++) {
        int r = ty + i * 8;
        tile[r][tx] = f2bf(xb[(size_t)(c0 + r) * Tt + t0 + tx]);
    }
    __syncthreads();
#pragma unroll
    for (int i = 0; i < 4; i++) {
        int r = ty + i * 8;
        int t = t0 + r;
        if (mask[b * Tt + t]) {
            int slot = pfx[b * Tt + t];
            xTb[(size_t)slot * Cc + c0 + tx] = tile[tx][r];
        }
    }
}

// ============ fused QKV GEMM on COMPACTED rows: 64m x 128n, BK=64 ============
// Smaller m-tile -> 768 live blocks (3/CU) instead of 384 (1.5/CU).
__global__ __launch_bounds__(256) void gemm_qkv(const u16* __restrict__ A,
                                                const u16* __restrict__ Bt,
                                                const float* __restrict__ b0,
                                                const float* __restrict__ b1,
                                                const float* __restrict__ b2,
                                                const int* __restrict__ nk,
                                                u16* __restrict__ qb, u16* __restrict__ kb,
                                                u16* __restrict__ vT) {
    constexpr int K = Cc;
    __shared__ u16 Alds[64 * 64];
    __shared__ u16 Blds[128 * 64];
    int n0 = blockIdx.x * 128, m0 = blockIdx.y * 64;
    int bb = m0 >> 11;
    if ((m0 & 2047) >= nk[bb]) return;
    int tid = threadIdx.x;
    int lane = tid & 63, wave = tid >> 6;
    int quad = lane >> 4, id15 = lane & 15;
    int wm0 = (wave & 1) * 32, wn0 = (wave >> 1) * 64;
    int sw = id15 & 7;

    f32x4 acc[4][2] = {};  // [ni][mi]

    for (int k0 = 0; k0 < K; k0 += 64) {
        __syncthreads();
#pragma unroll
        for (int i = 0; i < 2; i++) {
            int s = wave * 128 + i * 64 + lane;
            int r = s >> 3, c = (s & 7) ^ (r & 7);
            gl_lds16(A + (size_t)(m0 + r) * K + k0 + c * 8, &Alds[(wave * 128 + i * 64) * 8]);
        }
#pragma unroll
        for (int i = 0; i < 4; i++) {
            int s = wave * 256 + i * 64 + lane;
            int r = s >> 3, c = (s & 7) ^ (r & 7);
            gl_lds16(Bt + (size_t)(n0 + r) * K + k0 + c * 8, &Blds[(wave * 256 + i * 64) * 8]);
        }
        __syncthreads();
#pragma unroll
        for (int hf = 0; hf < 2; hf++) {
            int cc = (((hf << 2) | quad) ^ sw) * 8;
            bf16x8 af[2], bf[4];
#pragma unroll
            for (int mi = 0; mi < 2; mi++)
                af[mi] = *(const bf16x8*)(&Alds[(wm0 + mi * 16 + id15) * 64 + cc]);
#pragma unroll
            for (int ni = 0; ni < 4; ni++)
                bf[ni] = *(const bf16x8*)(&Blds[(wn0 + ni * 16 + id15) * 64 + cc]);
#pragma unroll
            for (int ni = 0; ni < 4; ni++)
#pragma unroll
                for (int mi = 0; mi < 2; mi++)
                    acc[ni][mi] = __builtin_amdgcn_mfma_f32_16x16x32_bf16(
                        bf[ni], af[mi], acc[ni][mi], 0, 0, 0);
        }
    }

    int mt0 = (m0 & 2047) + wm0;
#pragma unroll
    for (int ni = 0; ni < 4; ni++) {
        int nr = n0 + wn0 + ni * 16 + quad * 4;
        int sect = nr >> 10;
        int nn = nr & 1023;
        int h = nn >> 6, d0 = nn & 63;
        const float* bp_ = (sect == 0) ? b0 : (sect == 1) ? b1 : b2;
        float4 bv4 = *(const float4*)(bp_ + nn);
        if (sect < 2) {
            u16* dst = ((sect == 0) ? qb : kb) + ((size_t)bb * Hh + h) * Tt * (size_t)Dd;
#pragma unroll
            for (int mi = 0; mi < 2; mi++) {
                int mt = mt0 + mi * 16 + id15;
                uint2 w;
                w.x = pk_bf2(acc[ni][mi][0] + bv4.x, acc[ni][mi][1] + bv4.y);
                w.y = pk_bf2(acc[ni][mi][2] + bv4.z, acc[ni][mi][3] + bv4.w);
                *(uint2*)(dst + (size_t)mt * Dd + d0) = w;
            }
        } else {
            u16* dst = vT + ((size_t)bb * Hh + h) * Dd * (size_t)Tt;
#pragma unroll
            for (int mi = 0; mi < 2; mi++) {
                int mt = mt0 + mi * 16 + id15;
                dst[(size_t)(d0 + 0) * Tt + mt] = f2bf(acc[ni][mi][0] + bv4.x);
                dst[(size_t)(d0 + 1) * Tt + mt] = f2bf(acc[ni][mi][1] + bv4.y);
                dst[(size_t)(d0 + 2) * Tt + mt] = f2bf(acc[ni][mi][2] + bv4.z);
                dst[(size_t)(d0 + 3) * Tt + mt] = f2bf(acc[ni][mi][3] + bv4.w);
            }
        }
    }
}

// ============ proj GEMM (full-M): 64n x 64m, BK=64; (0,0) also writes mask tail ====
__global__ __launch_bounds__(256) void gemm_proj(const u16* __restrict__ A,
                                                 const u16* __restrict__ Bt,
                                                 const float* __restrict__ b0,
                                                 const int* __restrict__ mask,
                                                 float* __restrict__ out,
                                                 float* __restrict__ outTail) {
    constexpr int K = Cc;
    __shared__ u16 Alds[64 * 64];
    __shared__ u16 Blds[64 * 64];
    int n0 = blockIdx.x * 64, m0 = blockIdx.y * 64;
    int tid = threadIdx.x;
    if (outTail && blockIdx.x == 0 && blockIdx.y == 0) {
        for (int i = tid; i < Bb * Tt; i += 256) outTail[i] = mask[i] ? 1.0f : 0.0f;
    }
    int lane = tid & 63, wave = tid >> 6;
    int quad = lane >> 4, id15 = lane & 15;
    int wn0 = (wave & 1) * 32, wm0 = (wave >> 1) * 32;
    int sw = id15 & 7;

    f32x4 acc[2][2] = {};  // [ni][mi]

    for (int k0 = 0; k0 < K; k0 += 64) {
        __syncthreads();
#pragma unroll
        for (int i = 0; i < 2; i++) {
            int s = wave * 128 + i * 64 + lane;
            int r = s >> 3, c = (s & 7) ^ (r & 7);
            gl_lds16(A + (size_t)(m0 + r) * K + k0 + c * 8, &Alds[(wave * 128 + i * 64) * 8]);
            gl_lds16(Bt + (size_t)(n0 + r) * K + k0 + c * 8, &Blds[(wave * 128 + i * 64) * 8]);
        }
        __syncthreads();
#pragma unroll
        for (int hf = 0; hf < 2; hf++) {
            int cc = (((hf << 2) | quad) ^ sw) * 8;
            bf16x8 af[2], bf[2];
#pragma unroll
            for (int i = 0; i < 2; i++) {
                af[i] = *(const bf16x8*)(&Alds[(wm0 + i * 16 + id15) * 64 + cc]);
                bf[i] = *(const bf16x8*)(&Blds[(wn0 + i * 16 + id15) * 64 + cc]);
            }
#pragma unroll
            for (int ni = 0; ni < 2; ni++)
#pragma unroll
                for (int mi = 0; mi < 2; mi++)
                    acc[ni][mi] = __builtin_amdgcn_mfma_f32_16x16x32_bf16(
                        bf[ni], af[mi], acc[ni][mi], 0, 0, 0);
        }
    }

    int bb = m0 >> 11;
    int mt0 = (m0 & 2047) + wm0;
#pragma unroll
    for (int ni = 0; ni < 2; ni++) {
        int nr = n0 + wn0 + ni * 16 + quad * 4;
        float4 bv4 = *(const float4*)(b0 + nr);
#pragma unroll
        for (int mi = 0; mi < 2; mi++) {
            int m = mt0 + mi * 16 + id15;
            int mg = (bb << 11) + m;
            float mm = (float)mask[mg];
            float* o = out + ((size_t)bb * Cc + nr) * Tt + m;
            o[0 * Tt] = (acc[ni][mi][0] + bv4.x) * mm;
            o[1 * Tt] = (acc[ni][mi][1] + bv4.y) * mm;
            o[2 * Tt] = (acc[ni][mi][2] + bv4.z) * mm;
            o[3 * Tt] = (acc[ni][mi][3] + bv4.w) * mm;
        }
    }
}

// ---------------- attention: Q-tile 32, KEY-SPLIT x2 across wave pairs ----------------
// wave = kh*2 + qg: qg picks 16 queries, kh picks key half. Per-half single-buffered
// 64-key LDS chunks (32 KB total -> 5 blocks/CU; 1024 live blocks -> 16 waves/CU).
// Halves run lockstep over nch0 barrier iterations; dead iterations just barrier.
// Merge unnormalized O + l through the (then free) K LDS region.
__global__ __launch_bounds__(256) void attn(const u16* __restrict__ q,
                                            const u16* __restrict__ kk,
                                            const u16* __restrict__ vT,
                                            const int* __restrict__ tmap,
                                            const int* __restrict__ nk,
                                            u16* __restrict__ o_buf) {
    __shared__ u16 Kl[2][64 * 64];
    __shared__ u16 Vl[2][64 * 64];
    int bh = blockIdx.y;
    int b = bh >> 4, h = bh & 15;
    int t0 = blockIdx.x * 32;
    int nkb = nk[b];
    if (t0 >= nkb) return;
    int tid = threadIdx.x;
    int lane = tid & 63, wave = tid >> 6;
    int quad = lane >> 4, id15 = lane & 15;
    int qg = wave & 1, kh = wave >> 1;
    int wq = t0 + qg * 16;
    const u16* qb = q + (size_t)bh * Tt * Dd;
    const u16* kb = kk + (size_t)bh * Tt * Dd;
    const u16* vb = vT + (size_t)bh * Dd * Tt;

    // Q fragment (16 queries), 0.125 scale folded in
    union { uint4 r; bf16x8 v; } qf[2];
#pragma unroll
    for (int hf = 0; hf < 2; hf++) {
        uint4 r = *(const uint4*)(qb + (size_t)(wq + id15) * Dd + hf * 32 + quad * 8);
        qf[hf].r.x = scl2(r.x);
        qf[hf].r.y = scl2(r.y);
        qf[hf].r.z = scl2(r.z);
        qf[hf].r.w = scl2(r.w);
    }

    int nch = (nkb + 63) >> 6;
    int nch0 = (nch + 1) >> 1;
    int koff = kh ? nch0 * 64 : 0;
    int kend = kh ? nkb : ((nch0 * 64 < nkb) ? nch0 * 64 : nkb);

    float l = 0.0f;
    f32x4 accO[4] = {};
    int shA = ((quad & 1) * 2) * 16 + id15;
    int shB = shA + 16;
    const u16* Kb = Kl[kh];
    const u16* Vb = Vl[kh];

    for (int c = 0; c < nch0; c++) {
        int j0 = koff + c * 64;
        bool live = j0 < kend;
        __syncthreads();  // prev compute done (all 4 waves)
        if (live) {
#pragma unroll
            for (int i = 0; i < 4; i++) {
                int s = qg * 256 + i * 64 + lane;
                int r = s >> 3, cc = (s & 7) ^ (r & 7);
                gl_lds16(kb + (size_t)(j0 + r) * Dd + cc * 8,
                         &Kl[kh][(qg * 256 + i * 64) * 8]);
                gl_lds16(vb + (size_t)r * Tt + j0 + cc * 8,
                         &Vl[kh][(qg * 256 + i * 64) * 8]);
            }
        }
        __syncthreads();  // loads visible
        if (!live) continue;

        // S^T: 64 keys x 16 queries
        f32x4 st[4] = {};
#pragma unroll
        for (int kt = 0; kt < 4; kt++) {
            int krow = kt * 16 + id15;
#pragma unroll
            for (int hf = 0; hf < 2; hf++) {
                bf16x8 kf = *(const bf16x8*)(Kb + krow * 64 +
                                             (((hf << 2) | quad) ^ (krow & 7)) * 8);
                st[kt] = __builtin_amdgcn_mfma_f32_16x16x32_bf16(kf, qf[hf].v, st[kt], 0, 0, 0);
            }
        }
        // tail: dead key slots -> -inf before exp
        if (j0 + 64 > nkb) {
#pragma unroll
            for (int kt = 0; kt < 4; kt++) {
                int jb = j0 + kt * 16 + quad * 4;
#pragma unroll
                for (int r = 0; r < 4; r++)
                    if (jb + r >= nkb) st[kt][r] = -1e30f;
            }
        }

        u32 pkk[2][2][2];
#pragma unroll
        for (int kt = 0; kt < 4; kt++) {
            float p0 = __expf(st[kt][0]);
            float p1 = __expf(st[kt][1]);
            float p2 = __expf(st[kt][2]);
            float p3 = __expf(st[kt][3]);
            l += (p0 + p1) + (p2 + p3);
            pkk[kt >> 1][kt & 1][0] = pk_bf2(p0, p1);
            pkk[kt >> 1][kt & 1][1] = pk_bf2(p2, p3);
        }

#pragma unroll
        for (int g = 0; g < 2; g++) {
            union { u32 u[4]; bf16x8 v; } pf;
            u32 a0 = (u32)__shfl((int)pkk[g][0][0], shA);
            u32 a1 = (u32)__shfl((int)pkk[g][0][1], shA);
            u32 a2 = (u32)__shfl((int)pkk[g][0][0], shB);
            u32 a3 = (u32)__shfl((int)pkk[g][0][1], shB);
            u32 c0 = (u32)__shfl((int)pkk[g][1][0], shA);
            u32 c1 = (u32)__shfl((int)pkk[g][1][1], shA);
            u32 c2 = (u32)__shfl((int)pkk[g][1][0], shB);
            u32 c3 = (u32)__shfl((int)pkk[g][1][1], shB);
            pf.u[0] = (quad < 2) ? a0 : c0;
            pf.u[1] = (quad < 2) ? a1 : c1;
            pf.u[2] = (quad < 2) ? a2 : c2;
            pf.u[3] = (quad < 2) ? a3 : c3;
#pragma unroll
            for (int dt = 0; dt < 4; dt++) {
                int drow = dt * 16 + id15;
                bf16x8 vf = *(const bf16x8*)(Vb + drow * 64 +
                                             (((g << 2) | quad) ^ (drow & 7)) * 8);
                accO[dt] = __builtin_amdgcn_mfma_f32_16x16x32_bf16(vf, pf.v, accO[dt], 0, 0, 0);
            }
        }
    }

    // merge the two key halves through the now-free K LDS region
    __syncthreads();
    float* mb = (float*)&Kl[0][0];  // 16 KB, need 2*64*17*4 = 8.5 KB
    int base = (qg * 64 + lane) * 17;
    if (kh == 1) {
#pragma unroll
        for (int dt = 0; dt < 4; dt++)
#pragma unroll
            for (int r = 0; r < 4; r++) mb[base + dt * 4 + r] = accO[dt][r];
        mb[base + 16] = l;
    }
    __syncthreads();
    if (kh == 0) {
#pragma unroll
        for (int dt = 0; dt < 4; dt++)
#pragma unroll
            for (int r = 0; r < 4; r++) accO[dt][r] += mb[base + dt * 4 + r];
        l += mb[base + 16];
        l += __shfl_xor(l, 16);
        l += __shfl_xor(l, 32);
        float inv = 1.0f / l;
        int slot = wq + id15;
        bool ok = slot < nkb;
        int torig = ok ? tmap[b * Tt + slot] : 0;
        if (ok) {
#pragma unroll
            for (int dt = 0; dt < 4; dt++) {
                uint2 w;
                w.x = pk_bf2(accO[dt][0] * inv, accO[dt][1] * inv);
                w.y = pk_bf2(accO[dt][2] * inv, accO[dt][3] * inv);
                *(uint2*)(o_buf + ((size_t)b * Tt + torig) * Cc + h * Dd +
                          dt * 16 + quad * 4) = w;
            }
        }
    }
}

extern "C" void kernel_launch(void* const* d_in, const int* in_sizes, int n_in,
                              void* d_out, int out_size, void* d_ws, size_t ws_size,
                              hipStream_t stream) {
    const float* x  = (const float*)d_in[0];
    const int* mask = (const int*)d_in[1];
    const float* Wq = (const float*)d_in[2];
    const float* bq = (const float*)d_in[3];
    const float* Wk = (const float*)d_in[4];
    const float* bk = (const float*)d_in[5];
    const float* Wv = (const float*)d_in[6];
    const float* bv = (const float*)d_in[7];
    const float* Wp = (const float*)d_in[8];
    const float* bp = (const float*)d_in[9];
    float* out = (float*)d_out;

    size_t sz = (size_t)Bb * Tt * Cc;
    size_t wsz = (size_t)Cc * Cc;
    u16* xT = (u16*)d_ws;
    u16* qb = xT + sz;
    u16* kb = qb + sz;
    u16* vT = kb + sz;
    u16* wq16 = vT + sz;   // wq/wk/wv contiguous => fused [3072][1024] B matrix
    u16* wp16 = wq16 + 3 * wsz;
    int* pfx  = (int*)(wp16 + wsz);
    int* tmap = pfx + Bb * Tt;
    int* nkp  = tmap + Bb * Tt;
    u16* ob = xT;  // reuse xT region (stream-ordered)

    float* outTail = (out_size >= Bb * Cc * Tt + Bb * Tt)
                         ? out + (size_t)Bb * Cc * Tt : nullptr;

    prep<<<2 + 4 * (int)(wsz / 1024), 256, 0, stream>>>(
        mask, pfx, tmap, nkp, Wq, Wk, Wv, Wp, wq16);
    transpose_x<<<dim3(Tt / 32, Cc / 32, Bb), dim3(32, 8), 0, stream>>>(x, mask, pfx, xT);
    gemm_qkv<<<dim3(3 * Cc / 128, Bb * Tt / 64), 256, 0, stream>>>(
        xT, wq16, bq, bk, bv, nkp, qb, kb, vT);
    attn<<<dim3(Tt / 32, Bb * Hh), 256, 0, stream>>>(qb, kb, vT, tmap, nkp, ob);
    gemm_proj<<<dim3(Cc / 64, Bb * Tt / 64), 256, 0, stream>>>(
        ob, wp16, bp, mask, out, outTail);
}

// Round 11
// 169.637 us; speedup vs baseline: 1.1000x; 1.0882x over previous
//
#include <hip/hip_runtime.h>

typedef unsigned short u16;
typedef unsigned int u32;
typedef short bf16x8 __attribute__((ext_vector_type(8)));
typedef float f32x4 __attribute__((ext_vector_type(4)));

constexpr int Bb = 2, Cc = 1024, Tt = 2048, Hh = 16, Dd = 64;

__device__ __forceinline__ u16 f2bf(float f) {
    union { float f; u32 i; } c; c.f = f;
    u32 u = c.i;
    u32 r = (u + 0x7FFFu + ((u >> 16) & 1u)) >> 16;
    return (u16)r;
}
__device__ __forceinline__ u32 pk_bf2(float lo, float hi) {
    union { float f; u32 i; } a, b; a.f = lo; b.f = hi;
    u32 ua = a.i + 0x8000u, ub = b.i + 0x8000u;
    return (ub & 0xFFFF0000u) | (ua >> 16);
}
// scale packed bf16x2 by 0.125 exactly
__device__ __forceinline__ u32 scl2(u32 w) {
    union { float f; u32 i; } lo, hi;
    lo.i = w << 16; hi.i = w & 0xFFFF0000u;
    lo.f *= 0.125f; hi.f *= 0.125f;
    return (hi.i & 0xFFFF0000u) | (lo.i >> 16);
}
__device__ __forceinline__ void gl_lds16(const u16* g, u16* l) {
    __builtin_amdgcn_global_load_lds(
        (const __attribute__((address_space(1))) u32*)(const void*)g,
        (__attribute__((address_space(3))) u32*)(void*)l, 16, 0, 0);
}

// ------- prep: blocks 0..1 = per-batch mask scan; blocks 2.. = weight fp32->bf16 -------
__global__ __launch_bounds__(256) void prep(const int* __restrict__ mask,
                                            int* __restrict__ pfx,
                                            int* __restrict__ tmap,
                                            int* __restrict__ nk,
                                            const float* __restrict__ w0,
                                            const float* __restrict__ w1,
                                            const float* __restrict__ w2,
                                            const float* __restrict__ w3,
                                            u16* __restrict__ wout) {
    if (blockIdx.x < 2) {
        __shared__ int part[256];
        int b = blockIdx.x;
        const int* m = mask + b * Tt;
        int t8 = threadIdx.x * 8;
        int v[8], s = 0;
#pragma unroll
        for (int i = 0; i < 8; i++) { v[i] = m[t8 + i] ? 1 : 0; s += v[i]; }
        part[threadIdx.x] = s;
        __syncthreads();
        for (int off = 1; off < 256; off <<= 1) {
            int val = (threadIdx.x >= off) ? part[threadIdx.x - off] : 0;
            __syncthreads();
            part[threadIdx.x] += val;
            __syncthreads();
        }
        int run = part[threadIdx.x] - s;
#pragma unroll
        for (int i = 0; i < 8; i++) {
            pfx[b * Tt + t8 + i] = run;
            if (v[i]) { tmap[b * Tt + run] = t8 + i; run++; }
        }
        if (threadIdx.x == 255) nk[b] = part[255];
    } else {
        int bi = blockIdx.x - 2;
        int wsel = bi >> 10, blk = bi & 1023;
        const float* in = (wsel == 0) ? w0 : (wsel == 1) ? w1 : (wsel == 2) ? w2 : w3;
        u16* o = wout + (size_t)wsel * Cc * Cc;
        int i = (blk * 256 + threadIdx.x) * 4;
        float4 v = *(const float4*)(in + i);
        o[i + 0] = f2bf(v.x);
        o[i + 1] = f2bf(v.y);
        o[i + 2] = f2bf(v.z);
        o[i + 3] = f2bf(v.w);
    }
}

// ------- x transpose+convert+COMPACT: fp32 [b][c][t] -> bf16 xTc[b][pfx[t]][c] -------
__global__ __launch_bounds__(256) void transpose_x(const float* __restrict__ x,
                                                   const int* __restrict__ mask,
                                                   const int* __restrict__ pfx,
                                                   u16* __restrict__ xT) {
    __shared__ u16 tile[32][33];
    int b = blockIdx.z;
    int t0 = blockIdx.x * 32, c0 = blockIdx.y * 32;
    int tx = threadIdx.x, ty = threadIdx.y;
    const float* xb = x + (size_t)b * Cc * Tt;
    u16* xTb = xT + (size_t)b * Tt * Cc;
#pragma unroll
    for (int i = 0; i < 4; i++) {
        int r = ty + i * 8;
        tile[r][tx] = f2bf(xb[(size_t)(c0 + r) * Tt + t0 + tx]);
    }
    __syncthreads();
#pragma unroll
    for (int i = 0; i < 4; i++) {
        int r = ty + i * 8;
        int t = t0 + r;
        if (mask[b * Tt + t]) {
            int slot = pfx[b * Tt + t];
            xTb[(size_t)slot * Cc + c0 + tx] = tile[tx][r];
        }
    }
}

// ============ fused QKV GEMM on COMPACTED rows: 64m x 128n, BK=64 ============
// XCD swizzle: id = (n%8) + 8*(n/8 + 3*m)  -> XCD k owns weight strips {k,8+k,16+k}
// (768 KB, L2-resident); A-tile reused by 3 consecutive same-XCD blocks.
__global__ __launch_bounds__(256) void gemm_qkv(const u16* __restrict__ A,
                                                const u16* __restrict__ Bt,
                                                const float* __restrict__ b0,
                                                const float* __restrict__ b1,
                                                const float* __restrict__ b2,
                                                const int* __restrict__ nk,
                                                u16* __restrict__ qb, u16* __restrict__ kb,
                                                u16* __restrict__ vT) {
    constexpr int K = Cc;
    __shared__ u16 Alds[64 * 64];
    __shared__ u16 Blds[128 * 64];
    int id = blockIdx.x;
    int xcd = id & 7, qq = id >> 3;
    int nhi = qq % 3, mi_ = qq / 3;
    int n0 = (nhi * 8 + xcd) * 128;
    int m0 = mi_ * 64;
    int bb = m0 >> 11;
    if ((m0 & 2047) >= nk[bb]) return;
    int tid = threadIdx.x;
    int lane = tid & 63, wave = tid >> 6;
    int quad = lane >> 4, id15 = lane & 15;
    int wm0 = (wave & 1) * 32, wn0 = (wave >> 1) * 64;
    int sw = id15 & 7;

    f32x4 acc[4][2] = {};  // [ni][mi]

    for (int k0 = 0; k0 < K; k0 += 64) {
        __syncthreads();
#pragma unroll
        for (int i = 0; i < 2; i++) {
            int s = wave * 128 + i * 64 + lane;
            int r = s >> 3, c = (s & 7) ^ (r & 7);
            gl_lds16(A + (size_t)(m0 + r) * K + k0 + c * 8, &Alds[(wave * 128 + i * 64) * 8]);
        }
#pragma unroll
        for (int i = 0; i < 4; i++) {
            int s = wave * 256 + i * 64 + lane;
            int r = s >> 3, c = (s & 7) ^ (r & 7);
            gl_lds16(Bt + (size_t)(n0 + r) * K + k0 + c * 8, &Blds[(wave * 256 + i * 64) * 8]);
        }
        __syncthreads();
#pragma unroll
        for (int hf = 0; hf < 2; hf++) {
            int cc = (((hf << 2) | quad) ^ sw) * 8;
            bf16x8 af[2], bf[4];
#pragma unroll
            for (int mi = 0; mi < 2; mi++)
                af[mi] = *(const bf16x8*)(&Alds[(wm0 + mi * 16 + id15) * 64 + cc]);
#pragma unroll
            for (int ni = 0; ni < 4; ni++)
                bf[ni] = *(const bf16x8*)(&Blds[(wn0 + ni * 16 + id15) * 64 + cc]);
#pragma unroll
            for (int ni = 0; ni < 4; ni++)
#pragma unroll
                for (int mi = 0; mi < 2; mi++)
                    acc[ni][mi] = __builtin_amdgcn_mfma_f32_16x16x32_bf16(
                        bf[ni], af[mi], acc[ni][mi], 0, 0, 0);
        }
    }

    int mt0 = (m0 & 2047) + wm0;
#pragma unroll
    for (int ni = 0; ni < 4; ni++) {
        int nr = n0 + wn0 + ni * 16 + quad * 4;
        int sect = nr >> 10;
        int nn = nr & 1023;
        int h = nn >> 6, d0 = nn & 63;
        const float* bp_ = (sect == 0) ? b0 : (sect == 1) ? b1 : b2;
        float4 bv4 = *(const float4*)(bp_ + nn);
        if (sect < 2) {
            u16* dst = ((sect == 0) ? qb : kb) + ((size_t)bb * Hh + h) * Tt * (size_t)Dd;
#pragma unroll
            for (int mi = 0; mi < 2; mi++) {
                int mt = mt0 + mi * 16 + id15;
                uint2 w;
                w.x = pk_bf2(acc[ni][mi][0] + bv4.x, acc[ni][mi][1] + bv4.y);
                w.y = pk_bf2(acc[ni][mi][2] + bv4.z, acc[ni][mi][3] + bv4.w);
                *(uint2*)(dst + (size_t)mt * Dd + d0) = w;
            }
        } else {
            u16* dst = vT + ((size_t)bb * Hh + h) * Dd * (size_t)Tt;
#pragma unroll
            for (int mi = 0; mi < 2; mi++) {
                int mt = mt0 + mi * 16 + id15;
                dst[(size_t)(d0 + 0) * Tt + mt] = f2bf(acc[ni][mi][0] + bv4.x);
                dst[(size_t)(d0 + 1) * Tt + mt] = f2bf(acc[ni][mi][1] + bv4.y);
                dst[(size_t)(d0 + 2) * Tt + mt] = f2bf(acc[ni][mi][2] + bv4.z);
                dst[(size_t)(d0 + 3) * Tt + mt] = f2bf(acc[ni][mi][3] + bv4.w);
            }
        }
    }
}

// ============ proj GEMM (full-M): 64n x 64m, BK=64; id==0 also writes mask tail ====
// XCD swizzle: id = (n%8) + 8*(n/8 + 2*m) -> XCD k owns weight strips {k, 8+k}.
__global__ __launch_bounds__(256) void gemm_proj(const u16* __restrict__ A,
                                                 const u16* __restrict__ Bt,
                                                 const float* __restrict__ b0,
                                                 const int* __restrict__ mask,
                                                 float* __restrict__ out,
                                                 float* __restrict__ outTail) {
    constexpr int K = Cc;
    __shared__ u16 Alds[64 * 64];
    __shared__ u16 Blds[64 * 64];
    int id = blockIdx.x;
    int xcd = id & 7, qq = id >> 3;
    int nhi = qq & 1, mi_ = qq >> 1;
    int n0 = (nhi * 8 + xcd) * 64;
    int m0 = mi_ * 64;
    int tid = threadIdx.x;
    if (outTail && id == 0) {
        for (int i = tid; i < Bb * Tt; i += 256) outTail[i] = mask[i] ? 1.0f : 0.0f;
    }
    int lane = tid & 63, wave = tid >> 6;
    int quad = lane >> 4, id15 = lane & 15;
    int wn0 = (wave & 1) * 32, wm0 = (wave >> 1) * 32;
    int sw = id15 & 7;

    f32x4 acc[2][2] = {};  // [ni][mi]

    for (int k0 = 0; k0 < K; k0 += 64) {
        __syncthreads();
#pragma unroll
        for (int i = 0; i < 2; i++) {
            int s = wave * 128 + i * 64 + lane;
            int r = s >> 3, c = (s & 7) ^ (r & 7);
            gl_lds16(A + (size_t)(m0 + r) * K + k0 + c * 8, &Alds[(wave * 128 + i * 64) * 8]);
            gl_lds16(Bt + (size_t)(n0 + r) * K + k0 + c * 8, &Blds[(wave * 128 + i * 64) * 8]);
        }
        __syncthreads();
#pragma unroll
        for (int hf = 0; hf < 2; hf++) {
            int cc = (((hf << 2) | quad) ^ sw) * 8;
            bf16x8 af[2], bf[2];
#pragma unroll
            for (int i = 0; i < 2; i++) {
                af[i] = *(const bf16x8*)(&Alds[(wm0 + i * 16 + id15) * 64 + cc]);
                bf[i] = *(const bf16x8*)(&Blds[(wn0 + i * 16 + id15) * 64 + cc]);
            }
#pragma unroll
            for (int ni = 0; ni < 2; ni++)
#pragma unroll
                for (int mi = 0; mi < 2; mi++)
                    acc[ni][mi] = __builtin_amdgcn_mfma_f32_16x16x32_bf16(
                        bf[ni], af[mi], acc[ni][mi], 0, 0, 0);
        }
    }

    int bb = m0 >> 11;
    int mt0 = (m0 & 2047) + wm0;
#pragma unroll
    for (int ni = 0; ni < 2; ni++) {
        int nr = n0 + wn0 + ni * 16 + quad * 4;
        float4 bv4 = *(const float4*)(b0 + nr);
#pragma unroll
        for (int mi = 0; mi < 2; mi++) {
            int m = mt0 + mi * 16 + id15;
            int mg = (bb << 11) + m;
            float mm = (float)mask[mg];
            float* o = out + ((size_t)bb * Cc + nr) * Tt + m;
            o[0 * Tt] = (acc[ni][mi][0] + bv4.x) * mm;
            o[1 * Tt] = (acc[ni][mi][1] + bv4.y) * mm;
            o[2 * Tt] = (acc[ni][mi][2] + bv4.z) * mm;
            o[3 * Tt] = (acc[ni][mi][3] + bv4.w) * mm;
        }
    }
}

// ---------------- attention: Q-tile 32, KEY-SPLIT x2, XCD-pinned heads ----------------
// id = (bh%8) + 8*(t + 64*(bh/8)) -> XCD k owns heads {k,8+k,16+k,24+k}: their K/V
// (1 MB) stays L2-resident across the 64 consecutive same-XCD q-blocks.
__global__ __launch_bounds__(256) void attn(const u16* __restrict__ q,
                                            const u16* __restrict__ kk,
                                            const u16* __restrict__ vT,
                                            const int* __restrict__ tmap,
                                            const int* __restrict__ nk,
                                            u16* __restrict__ o_buf) {
    __shared__ u16 Kl[2][64 * 64];
    __shared__ u16 Vl[2][64 * 64];
    int id = blockIdx.x;
    int xcd = id & 7, qq = id >> 3;
    int t_idx = qq & 63, bhhi = qq >> 6;
    int bh = bhhi * 8 + xcd;
    int b = bh >> 4, h = bh & 15;
    int t0 = t_idx * 32;
    int nkb = nk[b];
    if (t0 >= nkb) return;
    int tid = threadIdx.x;
    int lane = tid & 63, wave = tid >> 6;
    int quad = lane >> 4, id15 = lane & 15;
    int qg = wave & 1, kh = wave >> 1;
    int wq = t0 + qg * 16;
    const u16* qb = q + (size_t)bh * Tt * Dd;
    const u16* kb = kk + (size_t)bh * Tt * Dd;
    const u16* vb = vT + (size_t)bh * Dd * Tt;

    // Q fragment (16 queries), 0.125 scale folded in
    union { uint4 r; bf16x8 v; } qf[2];
#pragma unroll
    for (int hf = 0; hf < 2; hf++) {
        uint4 r = *(const uint4*)(qb + (size_t)(wq + id15) * Dd + hf * 32 + quad * 8);
        qf[hf].r.x = scl2(r.x);
        qf[hf].r.y = scl2(r.y);
        qf[hf].r.z = scl2(r.z);
        qf[hf].r.w = scl2(r.w);
    }

    int nch = (nkb + 63) >> 6;
    int nch0 = (nch + 1) >> 1;
    int koff = kh ? nch0 * 64 : 0;
    int kend = kh ? nkb : ((nch0 * 64 < nkb) ? nch0 * 64 : nkb);

    float l = 0.0f;
    f32x4 accO[4] = {};
    int shA = ((quad & 1) * 2) * 16 + id15;
    int shB = shA + 16;
    const u16* Kb = Kl[kh];
    const u16* Vb = Vl[kh];

    for (int c = 0; c < nch0; c++) {
        int j0 = koff + c * 64;
        bool live = j0 < kend;
        __syncthreads();  // prev compute done (all 4 waves)
        if (live) {
#pragma unroll
            for (int i = 0; i < 4; i++) {
                int s = qg * 256 + i * 64 + lane;
                int r = s >> 3, cc = (s & 7) ^ (r & 7);
                gl_lds16(kb + (size_t)(j0 + r) * Dd + cc * 8,
                         &Kl[kh][(qg * 256 + i * 64) * 8]);
                gl_lds16(vb + (size_t)r * Tt + j0 + cc * 8,
                         &Vl[kh][(qg * 256 + i * 64) * 8]);
            }
        }
        __syncthreads();  // loads visible
        if (!live) continue;

        // S^T: 64 keys x 16 queries
        f32x4 st[4] = {};
#pragma unroll
        for (int kt = 0; kt < 4; kt++) {
            int krow = kt * 16 + id15;
#pragma unroll
            for (int hf = 0; hf < 2; hf++) {
                bf16x8 kf = *(const bf16x8*)(Kb + krow * 64 +
                                             (((hf << 2) | quad) ^ (krow & 7)) * 8);
                st[kt] = __builtin_amdgcn_mfma_f32_16x16x32_bf16(kf, qf[hf].v, st[kt], 0, 0, 0);
            }
        }
        // tail: dead key slots -> -inf before exp
        if (j0 + 64 > nkb) {
#pragma unroll
            for (int kt = 0; kt < 4; kt++) {
                int jb = j0 + kt * 16 + quad * 4;
#pragma unroll
                for (int r = 0; r < 4; r++)
                    if (jb + r >= nkb) st[kt][r] = -1e30f;
            }
        }

        u32 pkk[2][2][2];
#pragma unroll
        for (int kt = 0; kt < 4; kt++) {
            float p0 = __expf(st[kt][0]);
            float p1 = __expf(st[kt][1]);
            float p2 = __expf(st[kt][2]);
            float p3 = __expf(st[kt][3]);
            l += (p0 + p1) + (p2 + p3);
            pkk[kt >> 1][kt & 1][0] = pk_bf2(p0, p1);
            pkk[kt >> 1][kt & 1][1] = pk_bf2(p2, p3);
        }

#pragma unroll
        for (int g = 0; g < 2; g++) {
            union { u32 u[4]; bf16x8 v; } pf;
            u32 a0 = (u32)__shfl((int)pkk[g][0][0], shA);
            u32 a1 = (u32)__shfl((int)pkk[g][0][1], shA);
            u32 a2 = (u32)__shfl((int)pkk[g][0][0], shB);
            u32 a3 = (u32)__shfl((int)pkk[g][0][1], shB);
            u32 c0 = (u32)__shfl((int)pkk[g][1][0], shA);
            u32 c1 = (u32)__shfl((int)pkk[g][1][1], shA);
            u32 c2 = (u32)__shfl((int)pkk[g][1][0], shB);
            u32 c3 = (u32)__shfl((int)pkk[g][1][1], shB);
            pf.u[0] = (quad < 2) ? a0 : c0;
            pf.u[1] = (quad < 2) ? a1 : c1;
            pf.u[2] = (quad < 2) ? a2 : c2;
            pf.u[3] = (quad < 2) ? a3 : c3;
#pragma unroll
            for (int dt = 0; dt < 4; dt++) {
                int drow = dt * 16 + id15;
                bf16x8 vf = *(const bf16x8*)(Vb + drow * 64 +
                                             (((g << 2) | quad) ^ (drow & 7)) * 8);
                accO[dt] = __builtin_amdgcn_mfma_f32_16x16x32_bf16(vf, pf.v, accO[dt], 0, 0, 0);
            }
        }
    }

    // merge the two key halves through the now-free K LDS region
    __syncthreads();
    float* mb = (float*)&Kl[0][0];  // 16 KB, need 2*64*17*4 = 8.5 KB
    int base = (qg * 64 + lane) * 17;
    if (kh == 1) {
#pragma unroll
        for (int dt = 0; dt < 4; dt++)
#pragma unroll
            for (int r = 0; r < 4; r++) mb[base + dt * 4 + r] = accO[dt][r];
        mb[base + 16] = l;
    }
    __syncthreads();
    if (kh == 0) {
#pragma unroll
        for (int dt = 0; dt < 4; dt++)
#pragma unroll
            for (int r = 0; r < 4; r++) accO[dt][r] += mb[base + dt * 4 + r];
        l += mb[base + 16];
        l += __shfl_xor(l, 16);
        l += __shfl_xor(l, 32);
        float inv = 1.0f / l;
        int slot = wq + id15;
        bool ok = slot < nkb;
        int torig = ok ? tmap[b * Tt + slot] : 0;
        if (ok) {
#pragma unroll
            for (int dt = 0; dt < 4; dt++) {
                uint2 w;
                w.x = pk_bf2(accO[dt][0] * inv, accO[dt][1] * inv);
                w.y = pk_bf2(accO[dt][2] * inv, accO[dt][3] * inv);
                *(uint2*)(o_buf + ((size_t)b * Tt + torig) * Cc + h * Dd +
                          dt * 16 + quad * 4) = w;
            }
        }
    }
}

extern "C" void kernel_launch(void* const* d_in, const int* in_sizes, int n_in,
                              void* d_out, int out_size, void* d_ws, size_t ws_size,
                              hipStream_t stream) {
    const float* x  = (const float*)d_in[0];
    const int* mask = (const int*)d_in[1];
    const float* Wq = (const float*)d_in[2];
    const float* bq = (const float*)d_in[3];
    const float* Wk = (const float*)d_in[4];
    const float* bk = (const float*)d_in[5];
    const float* Wv = (const float*)d_in[6];
    const float* bv = (const float*)d_in[7];
    const float* Wp = (const float*)d_in[8];
    const float* bp = (const float*)d_in[9];
    float* out = (float*)d_out;

    size_t sz = (size_t)Bb * Tt * Cc;
    size_t wsz = (size_t)Cc * Cc;
    u16* xT = (u16*)d_ws;
    u16* qb = xT + sz;
    u16* kb = qb + sz;
    u16* vT = kb + sz;
    u16* wq16 = vT + sz;   // wq/wk/wv contiguous => fused [3072][1024] B matrix
    u16* wp16 = wq16 + 3 * wsz;
    int* pfx  = (int*)(wp16 + wsz);
    int* tmap = pfx + Bb * Tt;
    int* nkp  = tmap + Bb * Tt;
    u16* ob = xT;  // reuse xT region (stream-ordered)

    float* outTail = (out_size >= Bb * Cc * Tt + Bb * Tt)
                         ? out + (size_t)Bb * Cc * Tt : nullptr;

    prep<<<2 + 4 * (int)(wsz / 1024), 256, 0, stream>>>(
        mask, pfx, tmap, nkp, Wq, Wk, Wv, Wp, wq16);
    transpose_x<<<dim3(Tt / 32, Cc / 32, Bb), dim3(32, 8), 0, stream>>>(x, mask, pfx, xT);
    gemm_qkv<<<24 * 64, 256, 0, stream>>>(xT, wq16, bq, bk, bv, nkp, qb, kb, vT);
    attn<<<32 * 64, 256, 0, stream>>>(qb, kb, vT, tmap, nkp, ob);
    gemm_proj<<<16 * 64, 256, 0, stream>>>(ob, wp16, bp, mask, out, outTail);
}